// Round 15
// baseline (362.207 us; speedup 1.0000x reference)
//
#include <hip/hip_runtime.h>

#define HWsz 16384
#define Wd 128

typedef unsigned short ushortT;
typedef unsigned int uintT;
typedef __attribute__((ext_vector_type(8))) short short8v;
typedef __attribute__((ext_vector_type(4))) float f32x4;
typedef __attribute__((ext_vector_type(16))) float f32x16;
typedef __attribute__((ext_vector_type(4))) unsigned short ushort4v;

__device__ __forceinline__ float gelu_f(float x){
    return 0.5f * x * (1.0f + erff(x * 0.70710678118654752f));
}
__device__ __forceinline__ ushortT f2b(float f){
    union { float f; uintT u; } v; v.f = f;
    uintT r = v.u + 0x7FFFu + ((v.u >> 16) & 1u);   // RNE
    return (ushortT)(r >> 16);
}
__device__ __forceinline__ float b2f(ushortT u){
    union { uintT u; float f; } v; v.u = ((uintT)u) << 16; return v.f;
}
__device__ __forceinline__ void gload_lds16(const ushortT* g, ushortT* l){
    __builtin_amdgcn_global_load_lds(
        (const __attribute__((address_space(1))) void*)g,
        (__attribute__((address_space(3))) void*)l, 16, 0, 0);
}

// ============ merged weight packing ============
// conv3x3 weights: PADDED layout [nt][ch][tap][kg][BN+1][8] bf16 (pad slot -> bank-spread kg)
__device__ __forceinline__ void pack3p_one(int e, const float* __restrict__ w,
    ushortT* __restrict__ outp, int cout, int cin, int BN, int NCH)
{
    int j = e & 7; int r = e >> 3;
    int ocl = r % (BN+1); r /= (BN+1);
    int kg  = r & 3;  r >>= 2;
    int tap = r % 9;  r /= 9;
    int ch  = r % NCH;
    int nt  = r / NCH;
    int ci = ch*32 + kg*8 + j;
    int oc = nt*BN + ocl;
    float v = (ocl < BN && oc < cout && ci < cin) ? w[((size_t)oc*cin + ci)*9 + tap] : 0.f;
    outp[e] = f2b(v);
}
__device__ __forceinline__ void pack1_one(int e, const float* __restrict__ w,
    ushortT* __restrict__ outp, int cout, int cin, int BN, int NCH)
{
    int j = e & 7; int r = e >> 3;
    int ocl = r % BN; r /= BN;
    int kg  = r & 3;  r >>= 2;
    int ch  = r % NCH;
    int nt  = r / NCH;
    int ci = ch*32 + kg*8 + j;
    int oc = nt*BN + ocl;
    float v = (oc < cout && ci < cin) ? w[(size_t)oc*cin + ci] : 0.f;
    outp[e] = f2b(v);
}
// sizes (elems): L/R/Q = 2nt*3ch*9*4*49*8 = 84672 ; F = 6nt*8ch*9*4*49*8 = 677376
__global__ __launch_bounds__(256) void pack_all_kernel(
    const float* Lc, const float* Rc, const float* Qd, const float* Fd,
    const float* Q1, const float* KV1, const float* PI1, const float* FPO1,
    ushortT* dL, ushortT* dR, ushortT* dQ, ushortT* dF,
    ushortT* dq0, ushortT* dkv, ushortT* dpi, ushortT* dfpo)
{
    int e = blockIdx.x*256 + threadIdx.x;
    if      (e < 84672)  pack3p_one(e,        Lc, dL, 96, 96, 48, 3);
    else if (e < 169344) pack3p_one(e-84672,  Rc, dR, 96, 96, 48, 3);
    else if (e < 254016) pack3p_one(e-169344, Qd, dQ, 96, 96, 48, 3);
    else if (e < 931392) pack3p_one(e-254016, Fd, dF, 255,255, 48, 8);
    else if (e < 940608) pack1_one(e-931392, Q1, dq0, 96, 96, 96, 3);
    else if (e < 959040) pack1_one(e-940608, KV1,dkv, 192,96, 48, 3);
    else if (e < 983616) pack1_one(e-959040, PI1,dpi, 255,96, 64, 3);
    else if (e < 1008192) pack1_one(e-983616, FPO1,dfpo,96,255, 96, 8);
}

// ============ fused: x (NCHW fp32) -> xh (NHWC bf16) AND LN(n1) -> xnh (NHWC bf16) ============
__global__ __launch_bounds__(256) void tonhwc_ln_kernel(
    const float* __restrict__ in, const float* __restrict__ w,
    const float* __restrict__ bias, ushortT* __restrict__ xh,
    ushortT* __restrict__ xnh)
{
    const int p = blockIdx.x*256 + threadIdx.x;
    const int b = blockIdx.y;
    const float* ip = in + (size_t)b*96*HWsz + p;
    float v[96]; float s=0.f;
#pragma unroll
    for(int c=0;c<96;c++){ v[c]=ip[(size_t)c*HWsz]; s+=v[c]; }
    const float mu = s*(1.f/96.f);
    float s2=0.f;
#pragma unroll
    for(int c=0;c<96;c++){ float d=v[c]-mu; s2+=d*d; }
    const float inv = 1.f/sqrtf(s2*(1.f/96.f)+1e-5f);
    ushortT* op1 = xh  + ((size_t)b*HWsz + p)*96;
    ushortT* op2 = xnh + ((size_t)b*HWsz + p)*96;
#pragma unroll
    for (int g=0; g<12; g++){
        uint4 pk1, pk2; uintT a4[4], n4[4];
#pragma unroll
        for (int i=0;i<4;i++){
            float x0 = v[g*8+2*i], x1v = v[g*8+2*i+1];
            a4[i] = (uintT)f2b(x0) | ((uintT)f2b(x1v)<<16);
            float r0 = (x0-mu)*inv*w[g*8+2*i]+bias[g*8+2*i];
            float r1 = (x1v-mu)*inv*w[g*8+2*i+1]+bias[g*8+2*i+1];
            n4[i] = (uintT)f2b(r0) | ((uintT)f2b(r1)<<16);
        }
        pk1.x=a4[0]; pk1.y=a4[1]; pk1.z=a4[2]; pk1.w=a4[3];
        pk2.x=n4[0]; pk2.y=n4[1]; pk2.z=n4[2]; pk2.w=n4[3];
        *(uint4*)(op1 + g*8) = pk1;
        *(uint4*)(op2 + g*8) = pk2;
    }
}

// ============ conv3x3 v4: 16x16 pixel tile x ONE oc-slice; LDS weights (async, padded) ============
// 4 waves split 16 rows. grid (64, NT, B). NG=3 -> 48.9KB LDS -> 3 blocks/CU.
// TWOOUT=1: nt 0,1 -> out1; nt 2,3 -> out2. OMODE 1 = NHWC bf16, 2 = NCHW bf16.
template<int NG, int NCH, int ACT, int TWOOUT, int OMODE>
__global__ __launch_bounds__(256,3) void conv3x3_v4(
    const ushortT* __restrict__ inh,
    const ushortT* __restrict__ wpk1, const ushortT* __restrict__ wpk2,
    const float* __restrict__ bias1, const float* __restrict__ bias2,
    ushortT* __restrict__ out1, ushortT* __restrict__ out2,
    int cout, int ocpad)
{
    constexpr int BN = NG*16;
    constexpr int BNP = BN + 1;               // padded oc-row (bank-spread kg)
    constexpr int Cpad = NCH*32;
    constexpr int WCH4 = 9*4*BNP;             // uint4 per ch-chunk (padded)
    constexpr int WI = (WCH4 + 255)/256;
    __shared__ __align__(16) ushortT As[4*324*8];
    __shared__ __align__(16) ushortT Ws[WCH4*8];

    const int tid = threadIdx.x;
    const int l   = tid & 63;
    const int wv  = tid >> 6;
    const int l15 = l & 15;
    const int kg  = l >> 4;
    const int tix = blockIdx.x & 7, tiy = blockIdx.x >> 3;
    const int b   = blockIdx.z;
    const int x0 = tix*16, y0 = tiy*16;

    int nt = blockIdx.y;
    const ushortT* wpk; const float* bias; ushortT* outp; int ntw;
    if (TWOOUT && nt >= 2){ wpk = wpk2; bias = bias2; outp = out2; ntw = nt-2; }
    else { wpk = wpk1; bias = bias1; outp = out1; ntw = nt; }
    const int ocbase = ntw*BN;

    f32x4 acc[4][NG];
#pragma unroll
    for (int m=0;m<4;m++)
#pragma unroll
        for (int n=0;n<NG;n++) acc[m][n] = (f32x4){0.f,0.f,0.f,0.f};

    const ushortT* inb = inh + (size_t)b*HWsz*Cpad;

    for (int ch=0; ch<NCH; ch++){
        __syncthreads();
        for (int t=tid; t<1296; t+=256){
            int p = t>>2, g = t&3;
            int hy = p/18, hx = p - hy*18;
            int gy = y0 + hy - 1, gx = x0 + hx - 1;
            uint4 v; v.x=0u; v.y=0u; v.z=0u; v.w=0u;
            if ((unsigned)gy < 128u && (unsigned)gx < 128u)
                v = *(const uint4*)(inb + (size_t)(gy*Wd+gx)*Cpad + ch*32 + g*8);
            *(uint4*)(As + (g*324+p)*8) = v;
        }
        {
            const ushortT* wsrc = wpk + ((size_t)ntw*NCH + ch)*(WCH4*8);
#pragma unroll
            for (int i=0; i<WI; i++){
                int t = i*256 + tid;
                if ((WCH4 & 255) == 0 || t < WCH4)
                    gload_lds16(wsrc + (size_t)t*8, Ws + (size_t)t*8);
            }
        }
        __syncthreads();
#pragma unroll
        for (int tp=0; tp<9; tp++){
            const int dy = tp/3, dx = tp - dy*3;
            short8v bf[NG];
#pragma unroll
            for (int n=0;n<NG;n++)
                bf[n] = *(const short8v*)(Ws + ((size_t)(tp*4 + kg)*BNP + n*16 + l15)*8);
#pragma unroll
            for (int mg=0;mg<4;mg++){
                short8v a = *(const short8v*)(As + (kg*324 + (wv*4+mg+dy)*18 + l15+dx)*8);
#pragma unroll
                for (int n=0;n<NG;n++)
                    acc[mg][n] = __builtin_amdgcn_mfma_f32_16x16x32_bf16(a, bf[n], acc[mg][n], 0,0,0);
            }
        }
    }
    if (OMODE == 1){
        __syncthreads();
        ushortT* Ts = As + wv*1024;
#pragma unroll
        for (int mg=0;mg<4;mg++){
            int gy = y0 + wv*4 + mg;
            ushortT* orow = outp + ((size_t)b*HWsz + gy*Wd + x0)*ocpad + ocbase;
#pragma unroll
            for (int n=0;n<NG;n++){
                int ocl = n*16 + l15;
                int oc  = ocbase + ocl;
                float bs = (bias && oc < cout) ? bias[oc] : 0.f;
#pragma unroll
                for (int j=0;j<4;j++){
                    int pxj = kg*4 + j;
                    float r = 0.f;
                    if (oc < cout){ r = acc[mg][n][j] + bs; if (ACT) r = gelu_f(r); }
                    int seg = ((ocl>>3) + pxj) & 7;
                    Ts[pxj*64 + seg*8 + (ocl&7)] = f2b(r);
                }
            }
#pragma unroll
            for (int ps=0; ps < (BN+31)/32; ps++){
                int rpx = l & 15;
                int rs  = (l>>4) + ps*4;
                if (rs*8 < BN && ocbase + rs*8 + 8 <= ocpad){
                    int pseg = (rs + rpx) & 7;
                    short8v v = *(const short8v*)(Ts + rpx*64 + pseg*8);
                    *(short8v*)(orow + (size_t)rpx*ocpad + rs*8) = v;
                }
            }
        }
    } else {
#pragma unroll
        for (int n=0;n<NG;n++){
            int oc = ocbase + n*16 + l15;
            if (oc < cout){
                float bs = bias ? bias[oc] : 0.f;
#pragma unroll
                for (int mg=0;mg<4;mg++){
                    int gy = y0 + wv*4 + mg;
                    int gx = x0 + kg*4;
                    ushort4v pk;
#pragma unroll
                    for (int j=0;j<4;j++){
                        float r = acc[mg][n][j] + bs;
                        if (ACT) r = gelu_f(r);
                        pk[j] = f2b(r);
                    }
                    *(ushort4v*)(outp + ((size_t)b*cout + oc)*HWsz + gy*Wd + gx) = pk;
                }
            }
        }
    }
}

// ============ gemm1x1 v2: one block = 64 px x ALL output channels ============
template<int NGW, int NCH>
__global__ __launch_bounds__(256) void gemm1x1_v2(
    const ushortT* __restrict__ inh, const ushortT* __restrict__ wpk,
    ushortT* __restrict__ outp, int cout, int ocpad)
{
    constexpr int BN = NGW*16;
    constexpr int Cpad = NCH*32;
    __shared__ __align__(16) ushortT Ts[4*16*64];

    const int tid = threadIdx.x;
    const int l = tid & 63, wv = tid >> 6, l15 = l & 15, kg = l >> 4;
    const int p0 = blockIdx.x*64;
    const int b  = blockIdx.z;
    const int nt = wv, ocbase = wv*BN;
    const ushortT* inb = inh + (size_t)b*HWsz*Cpad;

    f32x4 acc[4][NGW];
#pragma unroll
    for (int m=0;m<4;m++)
#pragma unroll
        for (int n=0;n<NGW;n++) acc[m][n] = (f32x4){0.f,0.f,0.f,0.f};

#pragma unroll
    for (int ch=0; ch<NCH; ch++){
        short8v a[4], bw[NGW];
#pragma unroll
        for (int mg=0; mg<4; mg++)
            a[mg] = *(const short8v*)(inb + (size_t)(p0 + mg*16 + l15)*Cpad + ch*32 + kg*8);
#pragma unroll
        for (int n=0;n<NGW;n++)
            bw[n] = *(const short8v*)(wpk + (((size_t)(nt*NCH + ch)*4 + kg)*BN + n*16 + l15)*8);
#pragma unroll
        for (int mg=0;mg<4;mg++)
#pragma unroll
            for (int n=0;n<NGW;n++)
                acc[mg][n] = __builtin_amdgcn_mfma_f32_16x16x32_bf16(a[mg], bw[n], acc[mg][n], 0,0,0);
    }
    ushortT* Tw = Ts + wv*1024;
#pragma unroll
    for (int mg=0;mg<4;mg++){
        ushortT* orow = outp + ((size_t)b*HWsz + p0 + mg*16)*ocpad + ocbase;
#pragma unroll
        for (int n=0;n<NGW;n++){
            int ocl = n*16 + l15;
            int oc  = ocbase + ocl;
#pragma unroll
            for (int j=0;j<4;j++){
                int pxj = kg*4 + j;
                float r = (oc < cout) ? acc[mg][n][j] : 0.f;
                int seg = ((ocl>>3) + pxj) & 7;
                Tw[pxj*64 + seg*8 + (ocl&7)] = f2b(r);
            }
        }
#pragma unroll
        for (int ps=0; ps < (BN+31)/32; ps++){
            int rpx = l & 15;
            int rs  = (l>>4) + ps*4;
            if (rs*8 < BN){
                int pseg = (rs + rpx) & 7;
                short8v v = *(const short8v*)(Tw + rpx*64 + pseg*8);
                *(short8v*)(orow + (size_t)rpx*ocpad + rs*8) = v;
            }
        }
    }
}

// ============ gemm1x1 (q0 / fpo) ============
template<int NG, int NCH, int RES, int OMODE, int XMAP>
__global__ __launch_bounds__(256) void gemm1x1_mfma(
    const ushortT* __restrict__ inh, const ushortT* __restrict__ wpk, int wstride_z,
    const float* __restrict__ res1, const ushortT* __restrict__ res2b,
    void* __restrict__ outv, int cout, int ocpad)
{
    constexpr int BN = NG*16;
    constexpr int Cpad = NCH*32;
    constexpr int LSTR = (BN <= 64) ? 64 : 128;
    constexpr int MASK = LSTR/8 - 1;
    __shared__ __align__(16) ushortT TsS[(OMODE==1) ? 4*16*LSTR : 16];

    const int tid = threadIdx.x;
    const int l = tid & 63, wv = tid >> 6, l15 = l & 15, kg = l >> 4;
    int chunk = blockIdx.x, nt = blockIdx.y, b = blockIdx.z;
    const int p0 = chunk*256 + wv*64;
    const ushortT* inb = inh + (size_t)b*HWsz*Cpad;
    const ushortT* wp  = wpk + (size_t)b*wstride_z;

    f32x4 acc[4][NG];
#pragma unroll
    for (int m=0;m<4;m++)
#pragma unroll
        for (int n=0;n<NG;n++) acc[m][n] = (f32x4){0.f,0.f,0.f,0.f};

#pragma unroll
    for (int ch=0; ch<NCH; ch++){
        short8v a[4], bw[NG];
#pragma unroll
        for (int mg=0; mg<4; mg++)
            a[mg] = *(const short8v*)(inb + (size_t)(p0 + mg*16 + l15)*Cpad + ch*32 + kg*8);
#pragma unroll
        for (int n=0;n<NG;n++)
            bw[n] = *(const short8v*)(wp + (((size_t)(nt*NCH + ch)*4 + kg)*BN + n*16 + l15)*8);
#pragma unroll
        for (int mg=0;mg<4;mg++)
#pragma unroll
            for (int n=0;n<NG;n++)
                acc[mg][n] = __builtin_amdgcn_mfma_f32_16x16x32_bf16(a[mg], bw[n], acc[mg][n], 0,0,0);
    }
    if (OMODE == 0){
        float* out = (float*)outv;
#pragma unroll
        for (int n=0;n<NG;n++){
            int oc = nt*BN + n*16 + l15;
            if (oc < cout){
#pragma unroll
                for (int mg=0;mg<4;mg++){
                    int pix = p0 + mg*16 + kg*4;
                    size_t idx = ((size_t)b*cout + oc)*HWsz + pix;
                    float4 r;
                    r.x = acc[mg][n][0]; r.y = acc[mg][n][1];
                    r.z = acc[mg][n][2]; r.w = acc[mg][n][3];
                    if (RES>=1){ float4 q = *(const float4*)(res1+idx); r.x+=q.x;r.y+=q.y;r.z+=q.z;r.w+=q.w; }
                    if (RES>=2){
                        ushort4v q = *(const ushort4v*)(res2b+idx);
                        r.x+=b2f(q[0]); r.y+=b2f(q[1]); r.z+=b2f(q[2]); r.w+=b2f(q[3]);
                    }
                    *(float4*)(out + idx) = r;
                }
            }
        }
    } else {
        ushortT* outp = (ushortT*)outv;
        ushortT* Ts = TsS + wv*(16*LSTR);
#pragma unroll
        for (int mg=0;mg<4;mg++){
            ushortT* orow = outp + ((size_t)b*HWsz + p0 + mg*16)*ocpad + nt*BN;
#pragma unroll
            for (int n=0;n<NG;n++){
                int ocl = n*16 + l15;
                int oc  = nt*BN + ocl;
#pragma unroll
                for (int j=0;j<4;j++){
                    int pxj = kg*4 + j;
                    float r = (oc < cout) ? acc[mg][n][j] : 0.f;
                    int seg = ((ocl>>3) + pxj) & MASK;
                    Ts[pxj*LSTR + seg*8 + (ocl&7)] = f2b(r);
                }
            }
#pragma unroll
            for (int ps=0; ps < (BN+31)/32; ps++){
                int rpx = l & 15;
                int rs  = (l>>4) + ps*4;
                if (rs*8 < BN){
                    int pseg = (rs + rpx) & MASK;
                    short8v v = *(const short8v*)(Ts + rpx*LSTR + pseg*8);
                    *(short8v*)(orow + (size_t)rpx*ocpad + rs*8) = v;
                }
            }
        }
    }
}

// ============ fused pv+po + LayerNorm(n2), two-pass variance ============
__global__ __launch_bounds__(256) void pvpo_ln_kernel(
    const ushortT* __restrict__ vh, const ushortT* __restrict__ Mpk,
    const float* __restrict__ xres, const float* __restrict__ lnw,
    const float* __restrict__ lnb, float* __restrict__ x1out,
    ushortT* __restrict__ x2nh)
{
    constexpr int BN = 96, NG = 6, NCH = 3, Cpad = 96, LSTR = 128, MASK = 15;
    __shared__ __align__(16) ushortT TsS[4*16*LSTR];

    const int tid = threadIdx.x;
    const int l = tid & 63, wv = tid >> 6, l15 = l & 15, kg = l >> 4;
    const int b = blockIdx.z;
    const int p0 = blockIdx.x*256 + wv*64;
    const ushortT* inb = vh + (size_t)b*HWsz*Cpad;
    const ushortT* wp  = Mpk + (size_t)b*9216;

    f32x4 acc[4][NG];
#pragma unroll
    for (int m=0;m<4;m++)
#pragma unroll
        for (int n=0;n<NG;n++) acc[m][n] = (f32x4){0.f,0.f,0.f,0.f};

#pragma unroll
    for (int ch=0; ch<NCH; ch++){
        short8v a[4], bw[NG];
#pragma unroll
        for (int mg=0; mg<4; mg++)
            a[mg] = *(const short8v*)(inb + (size_t)(p0 + mg*16 + l15)*Cpad + ch*32 + kg*8);
#pragma unroll
        for (int n=0;n<NG;n++)
            bw[n] = *(const short8v*)(wp + (((size_t)ch*4 + kg)*BN + n*16 + l15)*8);
#pragma unroll
        for (int mg=0;mg<4;mg++)
#pragma unroll
            for (int n=0;n<NG;n++)
                acc[mg][n] = __builtin_amdgcn_mfma_f32_16x16x32_bf16(a[mg], bw[n], acc[mg][n], 0,0,0);
    }
#pragma unroll
    for (int mg=0;mg<4;mg++){
#pragma unroll
        for (int n=0;n<NG;n++){
            int oc = n*16 + l15;
            int pix = p0 + mg*16 + kg*4;
            size_t idx = ((size_t)b*96 + oc)*HWsz + pix;
            float4 q = *(const float4*)(xres+idx);
            acc[mg][n][0] += q.x; acc[mg][n][1] += q.y;
            acc[mg][n][2] += q.z; acc[mg][n][3] += q.w;
            float4 r;
            r.x = acc[mg][n][0]; r.y = acc[mg][n][1];
            r.z = acc[mg][n][2]; r.w = acc[mg][n][3];
            *(float4*)(x1out + idx) = r;
        }
    }
    float nv[4][NG][4];
#pragma unroll
    for (int mg=0;mg<4;mg++){
#pragma unroll
        for (int j=0;j<4;j++){
            float s = 0.f;
#pragma unroll
            for (int n=0;n<NG;n++) s += acc[mg][n][j];
#pragma unroll
            for (int m=1; m<16; m<<=1) s += __shfl_xor(s, m, 64);
            float mu = s*(1.f/96.f);
            float s2 = 0.f;
#pragma unroll
            for (int n=0;n<NG;n++){ float d = acc[mg][n][j]-mu; s2 += d*d; }
#pragma unroll
            for (int m=1; m<16; m<<=1) s2 += __shfl_xor(s2, m, 64);
            float inv = 1.f/sqrtf(s2*(1.f/96.f) + 1e-5f);
#pragma unroll
            for (int n=0;n<NG;n++){
                int oc = n*16 + l15;
                nv[mg][n][j] = (acc[mg][n][j]-mu)*inv*lnw[oc]+lnb[oc];
            }
        }
    }
    ushortT* Ts = TsS + wv*(16*LSTR);
#pragma unroll
    for (int mg=0;mg<4;mg++){
        ushortT* orow = x2nh + ((size_t)b*HWsz + p0 + mg*16)*96;
#pragma unroll
        for (int n=0;n<NG;n++){
            int ocl = n*16 + l15;
#pragma unroll
            for (int j=0;j<4;j++){
                int pxj = kg*4 + j;
                int seg = ((ocl>>3) + pxj) & MASK;
                Ts[pxj*LSTR + seg*8 + (ocl&7)] = f2b(nv[mg][n][j]);
            }
        }
#pragma unroll
        for (int ps=0; ps<3; ps++){
            int rpx = l & 15;
            int rs  = (l>>4) + ps*4;
            int pseg = (rs + rpx) & MASK;
            short8v v = *(const short8v*)(Ts + rpx*LSTR + pseg*8);
            *(short8v*)(orow + (size_t)rpx*96 + rs*8) = v;
        }
    }
}

// ============ head 1x1 (96 -> NOUT), NHWC bf16 in, NCHW fp32 out ============
template<int NOUT>
__global__ __launch_bounds__(256) void head1x1_kernel(
    const ushortT* __restrict__ inh, const float* __restrict__ w,
    const float* __restrict__ bias, float* __restrict__ out)
{
    __shared__ float lw[NOUT*96];
    const int tid = threadIdx.x;
    for (int t=tid; t<NOUT*96; t+=256) lw[t] = w[t];
    __syncthreads();
    const int p = blockIdx.x*256 + tid;
    const int b = blockIdx.y;
    const ushortT* ip = inh + ((size_t)b*HWsz + p)*96;
    float v[96];
#pragma unroll
    for (int g=0; g<12; g++){
        short8v s = *(const short8v*)(ip + g*8);
#pragma unroll
        for (int i=0;i<8;i++) v[g*8+i] = b2f((ushortT)s[i]);
    }
#pragma unroll
    for (int oc=0; oc<NOUT; oc++){
        float acc = bias[oc];
#pragma unroll
        for (int c=0;c<96;c++) acc += v[c]*lw[oc*96+c];
        out[((size_t)b*NOUT + oc)*HWsz + p] = acc;
    }
}

// ============ fused: Lr conv3x3(1->96)+bias+GELU + LayerNorm(nL) -> illh bf16 NHWC ============
__global__ __launch_bounds__(256) void lrein_ln_kernel(
    const float* __restrict__ L, const float* __restrict__ w,
    const float* __restrict__ bias, const float* __restrict__ lnw,
    const float* __restrict__ lnb, ushortT* __restrict__ outh)
{
    __shared__ float sw[864], sb[96], sn1[96], sn2[96];
    const int tid = threadIdx.x;
    for (int t=tid; t<864; t+=256) sw[t] = w[t];
    if (tid < 96){ sb[tid]=bias[tid]; sn1[tid]=lnw[tid]; sn2[tid]=lnb[tid]; }
    __syncthreads();
    const int p = blockIdx.x*256 + tid;
    const int b = blockIdx.y;
    const int y = p>>7, x = p&127;
    const float* ib = L + (size_t)b*HWsz;
    float win[9];
#pragma unroll
    for (int dy=0;dy<3;dy++)
#pragma unroll
        for (int dx=0;dx<3;dx++){
            int gy=y+dy-1, gx=x+dx-1;
            win[dy*3+dx] = ((unsigned)gy<128u && (unsigned)gx<128u) ? ib[gy*Wd+gx] : 0.f;
        }
    float v[96]; float s=0.f;
#pragma unroll
    for (int c=0;c<96;c++){
        float a = sb[c];
#pragma unroll
        for (int t=0;t<9;t++) a += win[t]*sw[c*9+t];
        a = gelu_f(a);
        v[c]=a; s+=a;
    }
    const float mu = s*(1.f/96.f);
    float s2=0.f;
#pragma unroll
    for (int c=0;c<96;c++){ float d=v[c]-mu; s2+=d*d; }
    const float inv = 1.f/sqrtf(s2*(1.f/96.f)+1e-5f);
    ushortT* op = outh + ((size_t)b*HWsz + p)*96;
#pragma unroll
    for (int g=0; g<12; g++){
        uint4 pk; uintT w4[4];
#pragma unroll
        for (int i=0;i<4;i++){
            float r0 = (v[g*8+2*i]-mu)*inv*sn1[g*8+2*i]+sn2[g*8+2*i];
            float r1 = (v[g*8+2*i+1]-mu)*inv*sn1[g*8+2*i+1]+sn2[g*8+2*i+1];
            w4[i] = (uintT)f2b(r0) | ((uintT)f2b(r1)<<16);
        }
        pk.x=w4[0]; pk.y=w4[1]; pk.z=w4[2]; pk.w=w4[3];
        *(uint4*)(op + g*8) = pk;
    }
}

// ============ Rr 3->96, 8 oc per block -> bf16 NCHW ============
__global__ __launch_bounds__(256) void conv3x3_rr_kernel(
    const float* __restrict__ in, const float* __restrict__ w,
    const float* __restrict__ bias, ushortT* __restrict__ out)
{
    __shared__ float sw[216], sb[8];
    const int oc0 = blockIdx.y*8;
    if (threadIdx.x < 216) sw[threadIdx.x] = w[(size_t)oc0*27 + threadIdx.x];
    if (threadIdx.x < 8)   sb[threadIdx.x] = bias[oc0 + threadIdx.x];
    __syncthreads();
    const int p = blockIdx.x*256+threadIdx.x;
    const int b = blockIdx.z;
    const int y=p>>7, x=p&127;
    const float* ib = in + (size_t)b*3*HWsz;
    float win[27];
#pragma unroll
    for (int ci=0;ci<3;ci++)
#pragma unroll
        for (int dy=0;dy<3;dy++)
#pragma unroll
            for (int dx=0;dx<3;dx++){
                int gy=y+dy-1, gx=x+dx-1;
                win[ci*9+dy*3+dx] = ((unsigned)gy<128u && (unsigned)gx<128u)
                    ? ib[(size_t)ci*HWsz + gy*Wd+gx] : 0.f;
            }
#pragma unroll
    for (int i=0;i<8;i++){
        float acc = sb[i];
#pragma unroll
        for (int t=0;t<27;t++) acc += win[t]*sw[i*27+t];
        out[((size_t)b*96 + oc0+i)*HWsz + p] = f2b(acc);
    }
}

// ============ depthwise 3x3 NHWC bf16; k-half -> bf16 NCHW, v-half -> bf16 NHWC ============
__global__ __launch_bounds__(256) void dw_nhwc_kernel(
    const ushortT* __restrict__ inh, const float* __restrict__ w,
    ushortT* __restrict__ kout, ushortT* __restrict__ vouth)
{
    const int p = blockIdx.x*256+threadIdx.x;
    const int c0 = blockIdx.y*8;
    const int b = blockIdx.z;
    const int y=p>>7, x=p&127;
    float lw[72];
#pragma unroll
    for (int i=0;i<8;i++)
#pragma unroll
        for (int t=0;t<9;t++) lw[i*9+t] = w[(size_t)(c0+i)*9 + t];
    const ushortT* ib = inh + (size_t)b*HWsz*192;
    float acc[8];
#pragma unroll
    for (int i=0;i<8;i++) acc[i]=0.f;
#pragma unroll
    for(int dy=0;dy<3;dy++){
        int gy=y+dy-1;
        if((unsigned)gy<128u){
#pragma unroll
            for(int dx=0;dx<3;dx++){
                int gx=x+dx-1;
                if((unsigned)gx<128u){
                    short8v s = *(const short8v*)(ib + (size_t)(gy*Wd+gx)*192 + c0);
#pragma unroll
                    for (int i=0;i<8;i++) acc[i] += b2f((ushortT)s[i])*lw[i*9+dy*3+dx];
                }
            }
        }
    }
    if (c0 < 96){
#pragma unroll
        for (int i=0;i<8;i++)
            kout[((size_t)b*96 + c0+i)*HWsz + p] = f2b(acc[i]);
    } else {
        ushortT* op = vouth + ((size_t)b*HWsz + p)*96 + (c0-96);
        uint4 pk;
        pk.x = (uintT)f2b(acc[0]) | ((uintT)f2b(acc[1])<<16);
        pk.y = (uintT)f2b(acc[2]) | ((uintT)f2b(acc[3])<<16);
        pk.z = (uintT)f2b(acc[4]) | ((uintT)f2b(acc[5])<<16);
        pk.w = (uintT)f2b(acc[6]) | ((uintT)f2b(acc[7])<<16);
        *(uint4*)op = pk;
    }
}

// ============ row L2-norm reciprocals for q/k (bf16 NCHW) ============
__global__ __launch_bounds__(256) void rownorm_bf16_kernel(
    const ushortT* __restrict__ qb, const ushortT* __restrict__ kb,
    float* __restrict__ invqk)
{
    __shared__ float red[256];
    const int r = blockIdx.x;       // 0..767
    const ushortT* ip = (r < 384) ? (qb + (size_t)r*HWsz) : (kb + (size_t)(r-384)*HWsz);
    float s=0.f;
    const ushortT* tp = ip + threadIdx.x*64;
#pragma unroll
    for (int g=0; g<8; g++){
        short8v v = *(const short8v*)(tp + g*8);
#pragma unroll
        for (int i=0;i<8;i++){ float f = b2f((ushortT)v[i]); s += f*f; }
    }
    red[threadIdx.x]=s; __syncthreads();
    for(int st=128; st>0; st>>=1){
        if(threadIdx.x<st) red[threadIdx.x]+=red[threadIdx.x+st];
        __syncthreads();
    }
    if(threadIdx.x==0) invqk[r] = 1.f/fmaxf(sqrtf(red[0]), 1e-12f);
}

// ============ QK^T Gram via MFMA 32x32x16 ============
__global__ __launch_bounds__(256) void qk_mfma_kernel(
    const ushortT* __restrict__ qb, const ushortT* __restrict__ kb,
    float* __restrict__ part)
{
    const int tid = threadIdx.x;
    const int l = tid & 63, wv = tid >> 6;
    const int chunk = blockIdx.x*4 + wv;          // 0..31
    const int bh = blockIdx.y, b = bh>>2, h = bh&3;
    const int ch = min(l & 31, 23);
    const int kh = (l >> 5)*8;
    const ushortT* qp = qb + ((size_t)b*96 + h*24 + ch)*HWsz + chunk*512 + kh;
    const ushortT* kp = kb + ((size_t)b*96 + h*24 + ch)*HWsz + chunk*512 + kh;
    f32x16 acc;
#pragma unroll
    for (int r=0;r<16;r++) acc[r]=0.f;
    for (int ks=0; ks<32; ks++){
        short8v a  = *(const short8v*)(qp + ks*16);
        short8v bb = *(const short8v*)(kp + ks*16);
        acc = __builtin_amdgcn_mfma_f32_32x32x16_bf16(a, bb, acc, 0,0,0);
    }
    float* op = part + ((size_t)chunk*16 + bh)*1024;
    const int col = l & 31;
#pragma unroll
    for (int r=0;r<16;r++){
        int row = (r&3) + 8*(r>>2) + 4*(l>>5);
        op[row*32 + col] = acc[r];
    }
}

// ============ softmax (fused chunk-reduce; norms + temp folded) ============
__global__ __launch_bounds__(576) void softmax_kernel(
    const float* __restrict__ part, const float* __restrict__ invq,
    const float* __restrict__ invk, const float* __restrict__ temp,
    float* __restrict__ attn)
{
    __shared__ float l[576];
    const int bh=blockIdx.x, b=bh>>2, h=bh&3;
    const int tid=threadIdx.x;
    const int i=tid/24, j=tid-i*24;
    float s=0.f;
    for (int c=0;c<32;c++) s += part[((size_t)c*16 + bh)*1024 + i*32 + j];
    l[tid] = s * invq[b*96+h*24+i] * invk[b*96+h*24+j] * temp[h];
    __syncthreads();
    if(tid<24){
        float m=-1e30f;
#pragma unroll
        for(int jj=0;jj<24;jj++) m = fmaxf(m, l[tid*24+jj]);
        float e[24]; float sm=0.f;
#pragma unroll
        for(int jj=0;jj<24;jj++){ e[jj]=__expf(l[tid*24+jj]-m); sm+=e[jj]; }
        float isv = 1.f/sm;
#pragma unroll
        for(int jj=0;jj<24;jj++) attn[(size_t)bh*576 + tid*24 + jj] = e[jj]*isv;
    }
}

// ============ M_b = po_w @ blockdiag(attn_b), packed to B-frag bf16 ============
__global__ __launch_bounds__(256) void mkM_kernel(
    const float* __restrict__ attn, const float* __restrict__ po_w,
    ushortT* __restrict__ Mpk)
{
    const int b = blockIdx.x;
    for (int e = threadIdx.x; e < 9216; e += 256){
        int oc = e / 96, d = e - oc*96;
        int h = d / 24, dl = d - h*24;
        const float* aw = attn + ((size_t)(b*4+h))*576 + dl;
        const float* pw = po_w + (size_t)oc*96 + h*24;
        float s = 0.f;
#pragma unroll
        for (int c=0;c<24;c++) s += pw[c]*aw[c*24];
        int ch = d>>5, kg = (d>>3)&3, j = d&7;
        Mpk[(size_t)b*9216 + ((size_t)(ch*4+kg)*96 + oc)*8 + j] = f2b(s);
    }
}

extern "C" void kernel_launch(void* const* d_in, const int* in_sizes, int n_in,
                              void* d_out, int out_size, void* d_ws, size_t ws_size,
                              hipStream_t stream)
{
    const float* x     = (const float*)d_in[0];
    const float* Lc_w1 = (const float*)d_in[1];
    const float* Lc_b1 = (const float*)d_in[2];
    const float* Lc_w2 = (const float*)d_in[3];
    const float* Lc_b2 = (const float*)d_in[4];
    const float* Rc_w1 = (const float*)d_in[5];
    const float* Rc_b1 = (const float*)d_in[6];
    const float* Rc_w2 = (const float*)d_in[7];
    const float* Rc_b2 = (const float*)d_in[8];
    const float* Lr_w  = (const float*)d_in[9];
    const float* Lr_b  = (const float*)d_in[10];
    const float* Rr_w  = (const float*)d_in[11];
    const float* Rr_b  = (const float*)d_in[12];
    const float* n1_w  = (const float*)d_in[13];
    const float* n1_b  = (const float*)d_in[14];
    const float* nL_w  = (const float*)d_in[15];
    const float* nL_b  = (const float*)d_in[16];
    const float* n2_w  = (const float*)d_in[17];
    const float* n2_b  = (const float*)d_in[18];
    const float* temp  = (const float*)d_in[19];
    const float* q_w   = (const float*)d_in[20];
    const float* qd_w  = (const float*)d_in[21];
    const float* kv_w  = (const float*)d_in[22];
    const float* kvd_w = (const float*)d_in[23];
    const float* po_w  = (const float*)d_in[24];
    const float* pi_w  = (const float*)d_in[25];
    const float* fdw_w = (const float*)d_in[26];
    const float* fpo_w = (const float*)d_in[27];

    char* base = (char*)d_ws;
    ushortT* xh   = (ushortT*)(base + 0);
    ushortT* f0h  = (ushortT*)(base + 0);
    ushortT* Lh   = (ushortT*)(base + 33554432);
    ushortT* kv0h = (ushortT*)(base + 33554432);
    ushortT* f1h  = (ushortT*)(base + 33554432);
    ushortT* Rh   = (ushortT*)(base + 67108864);
    ushortT* vh   = (ushortT*)(base + 67108864);
    ushortT* x2nh = (ushortT*)(base + 67108864);
    ushortT* illh = (ushortT*)(base + 79691776);
    ushortT* xnh  = (ushortT*)(base + 92274688);
    ushortT* q0h  = (ushortT*)(base + 104857600);
    ushortT* qb   = (ushortT*)(base + 117440512);
    float*   x1   = (float*)(base + 117440512);
    ushortT* kb   = (ushortT*)(base + 142606336);
    ushortT* Bb   = (ushortT*)(base + 155189248);
    char* smb = base + 167772160;
    ushortT* wpkL = (ushortT*)smb;   smb += 169344;
    ushortT* wpkR = (ushortT*)smb;   smb += 169344;
    ushortT* wpkQ = (ushortT*)smb;   smb += 169344;
    ushortT* wpkF = (ushortT*)smb;   smb += 1354752;
    ushortT* wq0  = (ushortT*)smb;   smb += 18432;
    ushortT* wkv  = (ushortT*)smb;   smb += 36864;
    ushortT* wpi  = (ushortT*)smb;   smb += 49152;
    ushortT* wfpo = (ushortT*)smb;   smb += 49152;
    ushortT* Mpk  = (ushortT*)smb;   smb += 73728;
    float* invqk  = (float*)smb;     smb += 3072;
    float* part   = (float*)smb;     smb += 2097152;
    float* attn   = (float*)smb;     smb += 36864;

    float* out_x = (float*)d_out;
    float* out_L = out_x + (size_t)4*96*HWsz;
    float* out_R = out_L + (size_t)4*HWsz;

    dim3 blk(256);

    // ---- packing + input convert (+ fused n1 LN) ----
    hipLaunchKernelGGL(pack_all_kernel, dim3(3938), blk, 0, stream,
        Lc_w1, Rc_w1, qd_w, fdw_w, q_w, kv_w, pi_w, fpo_w,
        wpkL, wpkR, wpkQ, wpkF, wq0, wkv, wpi, wfpo);
    hipLaunchKernelGGL(tonhwc_ln_kernel, dim3(64,4), blk, 0, stream, x, n1_w, n1_b, xh, xnh);

    // ---- Retinex heads (Lc+Rc, v4 single-tile, 3 blocks/CU) ----
    hipLaunchKernelGGL((conv3x3_v4<3,3,1,1,1>), dim3(64,4,4), blk, 0, stream,
        xh, wpkL, wpkR, Lc_b1, Rc_b1, Lh, Rh, 96, 96);
    hipLaunchKernelGGL((head1x1_kernel<1>), dim3(64,4), blk, 0, stream, Lh, Lc_w2, Lc_b2, out_L);
    hipLaunchKernelGGL((head1x1_kernel<3>), dim3(64,4), blk, 0, stream, Rh, Rc_w2, Rc_b2, out_R);
    hipLaunchKernelGGL(lrein_ln_kernel, dim3(64,4), blk, 0, stream, out_L, Lr_w, Lr_b, nL_w, nL_b, illh);
    hipLaunchKernelGGL(conv3x3_rr_kernel, dim3(64,12,4), blk, 0, stream, out_R, Rr_w, Rr_b, Bb);

    // ---- q path ----
    hipLaunchKernelGGL((gemm1x1_mfma<6,3,0,1,0>), dim3(64,1,4), blk, 0, stream,
        illh, wq0, 0, nullptr, nullptr, (void*)q0h, 96, 96);
    hipLaunchKernelGGL((conv3x3_v4<3,3,0,0,2>), dim3(64,2,4), blk, 0, stream,
        q0h, wpkQ, wpkQ, nullptr, nullptr, qb, qb, 96, 0);
    // ---- kv path ----
    hipLaunchKernelGGL((gemm1x1_v2<3,3>), dim3(256,1,4), blk, 0, stream,
        xnh, wkv, kv0h, 192, 192);
    hipLaunchKernelGGL(dw_nhwc_kernel, dim3(64,24,4), blk, 0, stream, kv0h, kvd_w, kb, vh);

    // ---- attention ----
    hipLaunchKernelGGL(rownorm_bf16_kernel, dim3(768), blk, 0, stream, qb, kb, invqk);
    hipLaunchKernelGGL(qk_mfma_kernel, dim3(8,16), blk, 0, stream, qb, kb, part);
    hipLaunchKernelGGL(softmax_kernel, dim3(16), dim3(576), 0, stream, part, invqk, invqk+384, temp, attn);
    hipLaunchKernelGGL(mkM_kernel, dim3(4), blk, 0, stream, attn, po_w, Mpk);
    // fused pv+po + LN(n2): x1 = x + M@v ; x2nh = LN(x1)
    hipLaunchKernelGGL(pvpo_ln_kernel, dim3(64,1,4), blk, 0, stream,
        vh, Mpk, x, n2_w, n2_b, x1, x2nh);

    // ---- FFN ----
    hipLaunchKernelGGL((gemm1x1_v2<4,3>), dim3(256,1,4), blk, 0, stream,
        x2nh, wpi, f0h, 255, 256);
    hipLaunchKernelGGL((conv3x3_v4<3,8,1,0,1>), dim3(64,6,4), blk, 0, stream,
        f0h, wpkF, wpkF, nullptr, nullptr, f1h, f1h, 255, 256);
    hipLaunchKernelGGL((gemm1x1_mfma<6,8,2,0,0>), dim3(64,1,4), blk, 0, stream,
        f1h, wfpo, 0, x1, Bb, (void*)out_x, 96, 0);
}

// Round 16
// 358.554 us; speedup vs baseline: 1.0102x; 1.0102x over previous
//
#include <hip/hip_runtime.h>

#define HWsz 16384
#define Wd 128

typedef unsigned short ushortT;
typedef unsigned int uintT;
typedef __attribute__((ext_vector_type(8))) short short8v;
typedef __attribute__((ext_vector_type(4))) float f32x4;
typedef __attribute__((ext_vector_type(16))) float f32x16;
typedef __attribute__((ext_vector_type(4))) unsigned short ushort4v;

__device__ __forceinline__ float gelu_f(float x){
    return 0.5f * x * (1.0f + erff(x * 0.70710678118654752f));
}
__device__ __forceinline__ ushortT f2b(float f){
    union { float f; uintT u; } v; v.f = f;
    uintT r = v.u + 0x7FFFu + ((v.u >> 16) & 1u);   // RNE
    return (ushortT)(r >> 16);
}
__device__ __forceinline__ float b2f(ushortT u){
    union { uintT u; float f; } v; v.u = ((uintT)u) << 16; return v.f;
}
__device__ __forceinline__ void gload_lds16(const ushortT* g, ushortT* l){
    __builtin_amdgcn_global_load_lds(
        (const __attribute__((address_space(1))) void*)g,
        (__attribute__((address_space(3))) void*)l, 16, 0, 0);
}

// ============ merged weight packing ============
__device__ __forceinline__ void pack3_one(int e, const float* __restrict__ w,
    ushortT* __restrict__ outp, int cout, int cin, int BN, int NCH)
{
    int j = e & 7; int r = e >> 3;
    int ocl = r % BN; r /= BN;
    int kg  = r & 3;  r >>= 2;
    int tap = r % 9;  r /= 9;
    int ch  = r % NCH;
    int nt  = r / NCH;
    int ci = ch*32 + kg*8 + j;
    int oc = nt*BN + ocl;
    float v = (oc < cout && ci < cin) ? w[((size_t)oc*cin + ci)*9 + tap] : 0.f;
    outp[e] = f2b(v);
}
__device__ __forceinline__ void pack1_one(int e, const float* __restrict__ w,
    ushortT* __restrict__ outp, int cout, int cin, int BN, int NCH)
{
    int j = e & 7; int r = e >> 3;
    int ocl = r % BN; r /= BN;
    int kg  = r & 3;  r >>= 2;
    int ch  = r % NCH;
    int nt  = r / NCH;
    int ci = ch*32 + kg*8 + j;
    int oc = nt*BN + ocl;
    float v = (oc < cout && ci < cin) ? w[(size_t)oc*cin + ci] : 0.f;
    outp[e] = f2b(v);
}
__global__ __launch_bounds__(256) void pack_all_kernel(
    const float* Lc, const float* Rc, const float* Qd, const float* Fd,
    const float* Q1, const float* KV1, const float* PI1, const float* FPO1,
    ushortT* dL, ushortT* dR, ushortT* dQ, ushortT* dF,
    ushortT* dq0, ushortT* dkv, ushortT* dpi, ushortT* dfpo)
{
    int e = blockIdx.x*256 + threadIdx.x;
    if      (e < 82944)  pack3_one(e,        Lc, dL, 96, 96, 48, 3);
    else if (e < 165888) pack3_one(e-82944,  Rc, dR, 96, 96, 48, 3);
    else if (e < 248832) pack3_one(e-165888, Qd, dQ, 96, 96, 48, 3);
    else if (e < 912384) pack3_one(e-248832, Fd, dF, 255,255, 48, 8);
    else if (e < 921600) pack1_one(e-912384, Q1, dq0, 96, 96, 96, 3);
    else if (e < 940032) pack1_one(e-921600, KV1,dkv, 192,96, 48, 3);
    else if (e < 964608) pack1_one(e-940032, PI1,dpi, 255,96, 64, 3);
    else if (e < 989184) pack1_one(e-964608, FPO1,dfpo,96,255, 96, 8);
}

// ============ fused: x (NCHW fp32) -> xh (NHWC bf16) AND LN(n1) -> xnh (NHWC bf16) ============
__global__ __launch_bounds__(256) void tonhwc_ln_kernel(
    const float* __restrict__ in, const float* __restrict__ w,
    const float* __restrict__ bias, ushortT* __restrict__ xh,
    ushortT* __restrict__ xnh)
{
    const int p = blockIdx.x*256 + threadIdx.x;
    const int b = blockIdx.y;
    const float* ip = in + (size_t)b*96*HWsz + p;
    float v[96]; float s=0.f;
#pragma unroll
    for(int c=0;c<96;c++){ v[c]=ip[(size_t)c*HWsz]; s+=v[c]; }
    const float mu = s*(1.f/96.f);
    float s2=0.f;
#pragma unroll
    for(int c=0;c<96;c++){ float d=v[c]-mu; s2+=d*d; }
    const float inv = 1.f/sqrtf(s2*(1.f/96.f)+1e-5f);
    ushortT* op1 = xh  + ((size_t)b*HWsz + p)*96;
    ushortT* op2 = xnh + ((size_t)b*HWsz + p)*96;
#pragma unroll
    for (int g=0; g<12; g++){
        uint4 pk1, pk2; uintT a4[4], n4[4];
#pragma unroll
        for (int i=0;i<4;i++){
            float x0 = v[g*8+2*i], x1v = v[g*8+2*i+1];
            a4[i] = (uintT)f2b(x0) | ((uintT)f2b(x1v)<<16);
            float r0 = (x0-mu)*inv*w[g*8+2*i]+bias[g*8+2*i];
            float r1 = (x1v-mu)*inv*w[g*8+2*i+1]+bias[g*8+2*i+1];
            n4[i] = (uintT)f2b(r0) | ((uintT)f2b(r1)<<16);
        }
        pk1.x=a4[0]; pk1.y=a4[1]; pk1.z=a4[2]; pk1.w=a4[3];
        pk2.x=n4[0]; pk2.y=n4[1]; pk2.z=n4[2]; pk2.w=n4[3];
        *(uint4*)(op1 + g*8) = pk1;
        *(uint4*)(op2 + g*8) = pk2;
    }
}

// ============ conv3x3 v4: 16x16 pixel tile x ONE oc-slice; LDS weights (async) ============
// 4 waves split 16 rows. grid (64, NT, B). NG=3 -> 48.4KB LDS -> 3 blocks/CU.
// TWOOUT=1: nt 0,1 -> out1; nt 2,3 -> out2. OMODE 1 = NHWC bf16, 2 = NCHW bf16.
template<int NG, int NCH, int ACT, int TWOOUT, int OMODE>
__global__ __launch_bounds__(256,3) void conv3x3_v4(
    const ushortT* __restrict__ inh,
    const ushortT* __restrict__ wpk1, const ushortT* __restrict__ wpk2,
    const float* __restrict__ bias1, const float* __restrict__ bias2,
    ushortT* __restrict__ out1, ushortT* __restrict__ out2,
    int cout, int ocpad)
{
    constexpr int BN = NG*16;
    constexpr int Cpad = NCH*32;
    constexpr int WCH4 = 9*4*BN;
    constexpr int WI = (WCH4 + 255)/256;
    __shared__ __align__(16) ushortT As[4*324*8];
    __shared__ __align__(16) ushortT Ws[WCH4*8];

    const int tid = threadIdx.x;
    const int l   = tid & 63;
    const int wv  = tid >> 6;
    const int l15 = l & 15;
    const int kg  = l >> 4;
    const int tix = blockIdx.x & 7, tiy = blockIdx.x >> 3;
    const int b   = blockIdx.z;
    const int x0 = tix*16, y0 = tiy*16;

    int nt = blockIdx.y;
    const ushortT* wpk; const float* bias; ushortT* outp; int ntw;
    if (TWOOUT && nt >= 2){ wpk = wpk2; bias = bias2; outp = out2; ntw = nt-2; }
    else { wpk = wpk1; bias = bias1; outp = out1; ntw = nt; }
    const int ocbase = ntw*BN;

    f32x4 acc[4][NG];
#pragma unroll
    for (int m=0;m<4;m++)
#pragma unroll
        for (int n=0;n<NG;n++) acc[m][n] = (f32x4){0.f,0.f,0.f,0.f};

    const ushortT* inb = inh + (size_t)b*HWsz*Cpad;

    for (int ch=0; ch<NCH; ch++){
        __syncthreads();
        for (int t=tid; t<1296; t+=256){
            int p = t>>2, g = t&3;
            int hy = p/18, hx = p - hy*18;
            int gy = y0 + hy - 1, gx = x0 + hx - 1;
            uint4 v; v.x=0u; v.y=0u; v.z=0u; v.w=0u;
            if ((unsigned)gy < 128u && (unsigned)gx < 128u)
                v = *(const uint4*)(inb + (size_t)(gy*Wd+gx)*Cpad + ch*32 + g*8);
            *(uint4*)(As + (g*324+p)*8) = v;
        }
        {
            const ushortT* wsrc = wpk + ((size_t)ntw*NCH + ch)*(WCH4*8);
#pragma unroll
            for (int i=0; i<WI; i++){
                int t = i*256 + tid;
                if ((WCH4 & 255) == 0 || t < WCH4)
                    gload_lds16(wsrc + (size_t)t*8, Ws + (size_t)t*8);
            }
        }
        __syncthreads();
#pragma unroll
        for (int tp=0; tp<9; tp++){
            const int dy = tp/3, dx = tp - dy*3;
            short8v bf[NG];
#pragma unroll
            for (int n=0;n<NG;n++)
                bf[n] = *(const short8v*)(Ws + ((size_t)(tp*4 + kg)*BN + n*16 + l15)*8);
#pragma unroll
            for (int mg=0;mg<4;mg++){
                short8v a = *(const short8v*)(As + (kg*324 + (wv*4+mg+dy)*18 + l15+dx)*8);
#pragma unroll
                for (int n=0;n<NG;n++)
                    acc[mg][n] = __builtin_amdgcn_mfma_f32_16x16x32_bf16(a, bf[n], acc[mg][n], 0,0,0);
            }
        }
    }
    if (OMODE == 1){
        __syncthreads();
        ushortT* Ts = As + wv*1024;
#pragma unroll
        for (int mg=0;mg<4;mg++){
            int gy = y0 + wv*4 + mg;
            ushortT* orow = outp + ((size_t)b*HWsz + gy*Wd + x0)*ocpad + ocbase;
#pragma unroll
            for (int n=0;n<NG;n++){
                int ocl = n*16 + l15;
                int oc  = ocbase + ocl;
                float bs = (bias && oc < cout) ? bias[oc] : 0.f;
#pragma unroll
                for (int j=0;j<4;j++){
                    int pxj = kg*4 + j;
                    float r = 0.f;
                    if (oc < cout){ r = acc[mg][n][j] + bs; if (ACT) r = gelu_f(r); }
                    int seg = ((ocl>>3) + pxj) & 7;
                    Ts[pxj*64 + seg*8 + (ocl&7)] = f2b(r);
                }
            }
#pragma unroll
            for (int ps=0; ps < (BN+31)/32; ps++){
                int rpx = l & 15;
                int rs  = (l>>4) + ps*4;
                if (rs*8 < BN && ocbase + rs*8 + 8 <= ocpad){
                    int pseg = (rs + rpx) & 7;
                    short8v v = *(const short8v*)(Ts + rpx*64 + pseg*8);
                    *(short8v*)(orow + (size_t)rpx*ocpad + rs*8) = v;
                }
            }
        }
    } else {
#pragma unroll
        for (int n=0;n<NG;n++){
            int oc = ocbase + n*16 + l15;
            if (oc < cout){
                float bs = bias ? bias[oc] : 0.f;
#pragma unroll
                for (int mg=0;mg<4;mg++){
                    int gy = y0 + wv*4 + mg;
                    int gx = x0 + kg*4;
                    ushort4v pk;
#pragma unroll
                    for (int j=0;j<4;j++){
                        float r = acc[mg][n][j] + bs;
                        if (ACT) r = gelu_f(r);
                        pk[j] = f2b(r);
                    }
                    *(ushort4v*)(outp + ((size_t)b*cout + oc)*HWsz + gy*Wd + gx) = pk;
                }
            }
        }
    }
}

// ============ gemm1x1 v2: one block = 64 px x ALL output channels ============
template<int NGW, int NCH>
__global__ __launch_bounds__(256) void gemm1x1_v2(
    const ushortT* __restrict__ inh, const ushortT* __restrict__ wpk,
    ushortT* __restrict__ outp, int cout, int ocpad)
{
    constexpr int BN = NGW*16;
    constexpr int Cpad = NCH*32;
    __shared__ __align__(16) ushortT Ts[4*16*64];

    const int tid = threadIdx.x;
    const int l = tid & 63, wv = tid >> 6, l15 = l & 15, kg = l >> 4;
    const int p0 = blockIdx.x*64;
    const int b  = blockIdx.z;
    const int nt = wv, ocbase = wv*BN;
    const ushortT* inb = inh + (size_t)b*HWsz*Cpad;

    f32x4 acc[4][NGW];
#pragma unroll
    for (int m=0;m<4;m++)
#pragma unroll
        for (int n=0;n<NGW;n++) acc[m][n] = (f32x4){0.f,0.f,0.f,0.f};

#pragma unroll
    for (int ch=0; ch<NCH; ch++){
        short8v a[4], bw[NGW];
#pragma unroll
        for (int mg=0; mg<4; mg++)
            a[mg] = *(const short8v*)(inb + (size_t)(p0 + mg*16 + l15)*Cpad + ch*32 + kg*8);
#pragma unroll
        for (int n=0;n<NGW;n++)
            bw[n] = *(const short8v*)(wpk + (((size_t)(nt*NCH + ch)*4 + kg)*BN + n*16 + l15)*8);
#pragma unroll
        for (int mg=0;mg<4;mg++)
#pragma unroll
            for (int n=0;n<NGW;n++)
                acc[mg][n] = __builtin_amdgcn_mfma_f32_16x16x32_bf16(a[mg], bw[n], acc[mg][n], 0,0,0);
    }
    ushortT* Tw = Ts + wv*1024;
#pragma unroll
    for (int mg=0;mg<4;mg++){
        ushortT* orow = outp + ((size_t)b*HWsz + p0 + mg*16)*ocpad + ocbase;
#pragma unroll
        for (int n=0;n<NGW;n++){
            int ocl = n*16 + l15;
            int oc  = ocbase + ocl;
#pragma unroll
            for (int j=0;j<4;j++){
                int pxj = kg*4 + j;
                float r = (oc < cout) ? acc[mg][n][j] : 0.f;
                int seg = ((ocl>>3) + pxj) & 7;
                Tw[pxj*64 + seg*8 + (ocl&7)] = f2b(r);
            }
        }
#pragma unroll
        for (int ps=0; ps < (BN+31)/32; ps++){
            int rpx = l & 15;
            int rs  = (l>>4) + ps*4;
            if (rs*8 < BN){
                int pseg = (rs + rpx) & 7;
                short8v v = *(const short8v*)(Tw + rpx*64 + pseg*8);
                *(short8v*)(orow + (size_t)rpx*ocpad + rs*8) = v;
            }
        }
    }
}

// ============ gemm1x1 (q0 / fpo) ============
template<int NG, int NCH, int RES, int OMODE, int XMAP>
__global__ __launch_bounds__(256) void gemm1x1_mfma(
    const ushortT* __restrict__ inh, const ushortT* __restrict__ wpk, int wstride_z,
    const float* __restrict__ res1, const ushortT* __restrict__ res2b,
    void* __restrict__ outv, int cout, int ocpad)
{
    constexpr int BN = NG*16;
    constexpr int Cpad = NCH*32;
    constexpr int LSTR = (BN <= 64) ? 64 : 128;
    constexpr int MASK = LSTR/8 - 1;
    __shared__ __align__(16) ushortT TsS[(OMODE==1) ? 4*16*LSTR : 16];

    const int tid = threadIdx.x;
    const int l = tid & 63, wv = tid >> 6, l15 = l & 15, kg = l >> 4;
    int chunk = blockIdx.x, nt = blockIdx.y, b = blockIdx.z;
    const int p0 = chunk*256 + wv*64;
    const ushortT* inb = inh + (size_t)b*HWsz*Cpad;
    const ushortT* wp  = wpk + (size_t)b*wstride_z;

    f32x4 acc[4][NG];
#pragma unroll
    for (int m=0;m<4;m++)
#pragma unroll
        for (int n=0;n<NG;n++) acc[m][n] = (f32x4){0.f,0.f,0.f,0.f};

#pragma unroll
    for (int ch=0; ch<NCH; ch++){
        short8v a[4], bw[NG];
#pragma unroll
        for (int mg=0; mg<4; mg++)
            a[mg] = *(const short8v*)(inb + (size_t)(p0 + mg*16 + l15)*Cpad + ch*32 + kg*8);
#pragma unroll
        for (int n=0;n<NG;n++)
            bw[n] = *(const short8v*)(wp + (((size_t)(nt*NCH + ch)*4 + kg)*BN + n*16 + l15)*8);
#pragma unroll
        for (int mg=0;mg<4;mg++)
#pragma unroll
            for (int n=0;n<NG;n++)
                acc[mg][n] = __builtin_amdgcn_mfma_f32_16x16x32_bf16(a[mg], bw[n], acc[mg][n], 0,0,0);
    }
    if (OMODE == 0){
        float* out = (float*)outv;
#pragma unroll
        for (int n=0;n<NG;n++){
            int oc = nt*BN + n*16 + l15;
            if (oc < cout){
#pragma unroll
                for (int mg=0;mg<4;mg++){
                    int pix = p0 + mg*16 + kg*4;
                    size_t idx = ((size_t)b*cout + oc)*HWsz + pix;
                    float4 r;
                    r.x = acc[mg][n][0]; r.y = acc[mg][n][1];
                    r.z = acc[mg][n][2]; r.w = acc[mg][n][3];
                    if (RES>=1){ float4 q = *(const float4*)(res1+idx); r.x+=q.x;r.y+=q.y;r.z+=q.z;r.w+=q.w; }
                    if (RES>=2){
                        ushort4v q = *(const ushort4v*)(res2b+idx);
                        r.x+=b2f(q[0]); r.y+=b2f(q[1]); r.z+=b2f(q[2]); r.w+=b2f(q[3]);
                    }
                    *(float4*)(out + idx) = r;
                }
            }
        }
    } else {
        ushortT* outp = (ushortT*)outv;
        ushortT* Ts = TsS + wv*(16*LSTR);
#pragma unroll
        for (int mg=0;mg<4;mg++){
            ushortT* orow = outp + ((size_t)b*HWsz + p0 + mg*16)*ocpad + nt*BN;
#pragma unroll
            for (int n=0;n<NG;n++){
                int ocl = n*16 + l15;
                int oc  = nt*BN + ocl;
#pragma unroll
                for (int j=0;j<4;j++){
                    int pxj = kg*4 + j;
                    float r = (oc < cout) ? acc[mg][n][j] : 0.f;
                    int seg = ((ocl>>3) + pxj) & MASK;
                    Ts[pxj*LSTR + seg*8 + (ocl&7)] = f2b(r);
                }
            }
#pragma unroll
            for (int ps=0; ps < (BN+31)/32; ps++){
                int rpx = l & 15;
                int rs  = (l>>4) + ps*4;
                if (rs*8 < BN){
                    int pseg = (rs + rpx) & MASK;
                    short8v v = *(const short8v*)(Ts + rpx*LSTR + pseg*8);
                    *(short8v*)(orow + (size_t)rpx*ocpad + rs*8) = v;
                }
            }
        }
    }
}

// ============ fused pv+po + LayerNorm(n2), two-pass variance ============
__global__ __launch_bounds__(256) void pvpo_ln_kernel(
    const ushortT* __restrict__ vh, const ushortT* __restrict__ Mpk,
    const float* __restrict__ xres, const float* __restrict__ lnw,
    const float* __restrict__ lnb, float* __restrict__ x1out,
    ushortT* __restrict__ x2nh)
{
    constexpr int BN = 96, NG = 6, NCH = 3, Cpad = 96, LSTR = 128, MASK = 15;
    __shared__ __align__(16) ushortT TsS[4*16*LSTR];

    const int tid = threadIdx.x;
    const int l = tid & 63, wv = tid >> 6, l15 = l & 15, kg = l >> 4;
    const int b = blockIdx.z;
    const int p0 = blockIdx.x*256 + wv*64;
    const ushortT* inb = vh + (size_t)b*HWsz*Cpad;
    const ushortT* wp  = Mpk + (size_t)b*9216;

    f32x4 acc[4][NG];
#pragma unroll
    for (int m=0;m<4;m++)
#pragma unroll
        for (int n=0;n<NG;n++) acc[m][n] = (f32x4){0.f,0.f,0.f,0.f};

#pragma unroll
    for (int ch=0; ch<NCH; ch++){
        short8v a[4], bw[NG];
#pragma unroll
        for (int mg=0; mg<4; mg++)
            a[mg] = *(const short8v*)(inb + (size_t)(p0 + mg*16 + l15)*Cpad + ch*32 + kg*8);
#pragma unroll
        for (int n=0;n<NG;n++)
            bw[n] = *(const short8v*)(wp + (((size_t)ch*4 + kg)*BN + n*16 + l15)*8);
#pragma unroll
        for (int mg=0;mg<4;mg++)
#pragma unroll
            for (int n=0;n<NG;n++)
                acc[mg][n] = __builtin_amdgcn_mfma_f32_16x16x32_bf16(a[mg], bw[n], acc[mg][n], 0,0,0);
    }
#pragma unroll
    for (int mg=0;mg<4;mg++){
#pragma unroll
        for (int n=0;n<NG;n++){
            int oc = n*16 + l15;
            int pix = p0 + mg*16 + kg*4;
            size_t idx = ((size_t)b*96 + oc)*HWsz + pix;
            float4 q = *(const float4*)(xres+idx);
            acc[mg][n][0] += q.x; acc[mg][n][1] += q.y;
            acc[mg][n][2] += q.z; acc[mg][n][3] += q.w;
            float4 r;
            r.x = acc[mg][n][0]; r.y = acc[mg][n][1];
            r.z = acc[mg][n][2]; r.w = acc[mg][n][3];
            *(float4*)(x1out + idx) = r;
        }
    }
    float nv[4][NG][4];
#pragma unroll
    for (int mg=0;mg<4;mg++){
#pragma unroll
        for (int j=0;j<4;j++){
            float s = 0.f;
#pragma unroll
            for (int n=0;n<NG;n++) s += acc[mg][n][j];
#pragma unroll
            for (int m=1; m<16; m<<=1) s += __shfl_xor(s, m, 64);
            float mu = s*(1.f/96.f);
            float s2 = 0.f;
#pragma unroll
            for (int n=0;n<NG;n++){ float d = acc[mg][n][j]-mu; s2 += d*d; }
#pragma unroll
            for (int m=1; m<16; m<<=1) s2 += __shfl_xor(s2, m, 64);
            float inv = 1.f/sqrtf(s2*(1.f/96.f) + 1e-5f);
#pragma unroll
            for (int n=0;n<NG;n++){
                int oc = n*16 + l15;
                nv[mg][n][j] = (acc[mg][n][j]-mu)*inv*lnw[oc]+lnb[oc];
            }
        }
    }
    ushortT* Ts = TsS + wv*(16*LSTR);
#pragma unroll
    for (int mg=0;mg<4;mg++){
        ushortT* orow = x2nh + ((size_t)b*HWsz + p0 + mg*16)*96;
#pragma unroll
        for (int n=0;n<NG;n++){
            int ocl = n*16 + l15;
#pragma unroll
            for (int j=0;j<4;j++){
                int pxj = kg*4 + j;
                int seg = ((ocl>>3) + pxj) & MASK;
                Ts[pxj*LSTR + seg*8 + (ocl&7)] = f2b(nv[mg][n][j]);
            }
        }
#pragma unroll
        for (int ps=0; ps<3; ps++){
            int rpx = l & 15;
            int rs  = (l>>4) + ps*4;
            int pseg = (rs + rpx) & MASK;
            short8v v = *(const short8v*)(Ts + rpx*LSTR + pseg*8);
            *(short8v*)(orow + (size_t)rpx*96 + rs*8) = v;
        }
    }
}

// ============ head 1x1 (96 -> NOUT), NHWC bf16 in, NCHW fp32 out ============
template<int NOUT>
__global__ __launch_bounds__(256) void head1x1_kernel(
    const ushortT* __restrict__ inh, const float* __restrict__ w,
    const float* __restrict__ bias, float* __restrict__ out)
{
    __shared__ float lw[NOUT*96];
    const int tid = threadIdx.x;
    for (int t=tid; t<NOUT*96; t+=256) lw[t] = w[t];
    __syncthreads();
    const int p = blockIdx.x*256 + tid;
    const int b = blockIdx.y;
    const ushortT* ip = inh + ((size_t)b*HWsz + p)*96;
    float v[96];
#pragma unroll
    for (int g=0; g<12; g++){
        short8v s = *(const short8v*)(ip + g*8);
#pragma unroll
        for (int i=0;i<8;i++) v[g*8+i] = b2f((ushortT)s[i]);
    }
#pragma unroll
    for (int oc=0; oc<NOUT; oc++){
        float acc = bias[oc];
#pragma unroll
        for (int c=0;c<96;c++) acc += v[c]*lw[oc*96+c];
        out[((size_t)b*NOUT + oc)*HWsz + p] = acc;
    }
}

// ============ fused: Lr conv3x3(1->96)+bias+GELU + LayerNorm(nL) -> illh bf16 NHWC ============
__global__ __launch_bounds__(256) void lrein_ln_kernel(
    const float* __restrict__ L, const float* __restrict__ w,
    const float* __restrict__ bias, const float* __restrict__ lnw,
    const float* __restrict__ lnb, ushortT* __restrict__ outh)
{
    __shared__ float sw[864], sb[96], sn1[96], sn2[96];
    const int tid = threadIdx.x;
    for (int t=tid; t<864; t+=256) sw[t] = w[t];
    if (tid < 96){ sb[tid]=bias[tid]; sn1[tid]=lnw[tid]; sn2[tid]=lnb[tid]; }
    __syncthreads();
    const int p = blockIdx.x*256 + tid;
    const int b = blockIdx.y;
    const int y = p>>7, x = p&127;
    const float* ib = L + (size_t)b*HWsz;
    float win[9];
#pragma unroll
    for (int dy=0;dy<3;dy++)
#pragma unroll
        for (int dx=0;dx<3;dx++){
            int gy=y+dy-1, gx=x+dx-1;
            win[dy*3+dx] = ((unsigned)gy<128u && (unsigned)gx<128u) ? ib[gy*Wd+gx] : 0.f;
        }
    float v[96]; float s=0.f;
#pragma unroll
    for (int c=0;c<96;c++){
        float a = sb[c];
#pragma unroll
        for (int t=0;t<9;t++) a += win[t]*sw[c*9+t];
        a = gelu_f(a);
        v[c]=a; s+=a;
    }
    const float mu = s*(1.f/96.f);
    float s2=0.f;
#pragma unroll
    for (int c=0;c<96;c++){ float d=v[c]-mu; s2+=d*d; }
    const float inv = 1.f/sqrtf(s2*(1.f/96.f)+1e-5f);
    ushortT* op = outh + ((size_t)b*HWsz + p)*96;
#pragma unroll
    for (int g=0; g<12; g++){
        uint4 pk; uintT w4[4];
#pragma unroll
        for (int i=0;i<4;i++){
            float r0 = (v[g*8+2*i]-mu)*inv*sn1[g*8+2*i]+sn2[g*8+2*i];
            float r1 = (v[g*8+2*i+1]-mu)*inv*sn1[g*8+2*i+1]+sn2[g*8+2*i+1];
            w4[i] = (uintT)f2b(r0) | ((uintT)f2b(r1)<<16);
        }
        pk.x=w4[0]; pk.y=w4[1]; pk.z=w4[2]; pk.w=w4[3];
        *(uint4*)(op + g*8) = pk;
    }
}

// ============ Rr 3->96, 8 oc per block -> bf16 NCHW ============
__global__ __launch_bounds__(256) void conv3x3_rr_kernel(
    const float* __restrict__ in, const float* __restrict__ w,
    const float* __restrict__ bias, ushortT* __restrict__ out)
{
    __shared__ float sw[216], sb[8];
    const int oc0 = blockIdx.y*8;
    if (threadIdx.x < 216) sw[threadIdx.x] = w[(size_t)oc0*27 + threadIdx.x];
    if (threadIdx.x < 8)   sb[threadIdx.x] = bias[oc0 + threadIdx.x];
    __syncthreads();
    const int p = blockIdx.x*256+threadIdx.x;
    const int b = blockIdx.z;
    const int y=p>>7, x=p&127;
    const float* ib = in + (size_t)b*3*HWsz;
    float win[27];
#pragma unroll
    for (int ci=0;ci<3;ci++)
#pragma unroll
        for (int dy=0;dy<3;dy++)
#pragma unroll
            for (int dx=0;dx<3;dx++){
                int gy=y+dy-1, gx=x+dx-1;
                win[ci*9+dy*3+dx] = ((unsigned)gy<128u && (unsigned)gx<128u)
                    ? ib[(size_t)ci*HWsz + gy*Wd+gx] : 0.f;
            }
#pragma unroll
    for (int i=0;i<8;i++){
        float acc = sb[i];
#pragma unroll
        for (int t=0;t<27;t++) acc += win[t]*sw[i*27+t];
        out[((size_t)b*96 + oc0+i)*HWsz + p] = f2b(acc);
    }
}

// ============ depthwise 3x3 NHWC bf16; k-half -> bf16 NCHW, v-half -> bf16 NHWC ============
__global__ __launch_bounds__(256) void dw_nhwc_kernel(
    const ushortT* __restrict__ inh, const float* __restrict__ w,
    ushortT* __restrict__ kout, ushortT* __restrict__ vouth)
{
    const int p = blockIdx.x*256+threadIdx.x;
    const int c0 = blockIdx.y*8;
    const int b = blockIdx.z;
    const int y=p>>7, x=p&127;
    float lw[72];
#pragma unroll
    for (int i=0;i<8;i++)
#pragma unroll
        for (int t=0;t<9;t++) lw[i*9+t] = w[(size_t)(c0+i)*9 + t];
    const ushortT* ib = inh + (size_t)b*HWsz*192;
    float acc[8];
#pragma unroll
    for (int i=0;i<8;i++) acc[i]=0.f;
#pragma unroll
    for(int dy=0;dy<3;dy++){
        int gy=y+dy-1;
        if((unsigned)gy<128u){
#pragma unroll
            for(int dx=0;dx<3;dx++){
                int gx=x+dx-1;
                if((unsigned)gx<128u){
                    short8v s = *(const short8v*)(ib + (size_t)(gy*Wd+gx)*192 + c0);
#pragma unroll
                    for (int i=0;i<8;i++) acc[i] += b2f((ushortT)s[i])*lw[i*9+dy*3+dx];
                }
            }
        }
    }
    if (c0 < 96){
#pragma unroll
        for (int i=0;i<8;i++)
            kout[((size_t)b*96 + c0+i)*HWsz + p] = f2b(acc[i]);
    } else {
        ushortT* op = vouth + ((size_t)b*HWsz + p)*96 + (c0-96);
        uint4 pk;
        pk.x = (uintT)f2b(acc[0]) | ((uintT)f2b(acc[1])<<16);
        pk.y = (uintT)f2b(acc[2]) | ((uintT)f2b(acc[3])<<16);
        pk.z = (uintT)f2b(acc[4]) | ((uintT)f2b(acc[5])<<16);
        pk.w = (uintT)f2b(acc[6]) | ((uintT)f2b(acc[7])<<16);
        *(uint4*)op = pk;
    }
}

// ============ row L2-norm reciprocals for q/k (bf16 NCHW) ============
__global__ __launch_bounds__(256) void rownorm_bf16_kernel(
    const ushortT* __restrict__ qb, const ushortT* __restrict__ kb,
    float* __restrict__ invqk)
{
    __shared__ float red[256];
    const int r = blockIdx.x;       // 0..767
    const ushortT* ip = (r < 384) ? (qb + (size_t)r*HWsz) : (kb + (size_t)(r-384)*HWsz);
    float s=0.f;
    const ushortT* tp = ip + threadIdx.x*64;
#pragma unroll
    for (int g=0; g<8; g++){
        short8v v = *(const short8v*)(tp + g*8);
#pragma unroll
        for (int i=0;i<8;i++){ float f = b2f((ushortT)v[i]); s += f*f; }
    }
    red[threadIdx.x]=s; __syncthreads();
    for(int st=128; st>0; st>>=1){
        if(threadIdx.x<st) red[threadIdx.x]+=red[threadIdx.x+st];
        __syncthreads();
    }
    if(threadIdx.x==0) invqk[r] = 1.f/fmaxf(sqrtf(red[0]), 1e-12f);
}

// ============ QK^T Gram via MFMA 32x32x16 ============
__global__ __launch_bounds__(256) void qk_mfma_kernel(
    const ushortT* __restrict__ qb, const ushortT* __restrict__ kb,
    float* __restrict__ part)
{
    const int tid = threadIdx.x;
    const int l = tid & 63, wv = tid >> 6;
    const int chunk = blockIdx.x*4 + wv;          // 0..31
    const int bh = blockIdx.y, b = bh>>2, h = bh&3;
    const int ch = min(l & 31, 23);
    const int kh = (l >> 5)*8;
    const ushortT* qp = qb + ((size_t)b*96 + h*24 + ch)*HWsz + chunk*512 + kh;
    const ushortT* kp = kb + ((size_t)b*96 + h*24 + ch)*HWsz + chunk*512 + kh;
    f32x16 acc;
#pragma unroll
    for (int r=0;r<16;r++) acc[r]=0.f;
    for (int ks=0; ks<32; ks++){
        short8v a  = *(const short8v*)(qp + ks*16);
        short8v bb = *(const short8v*)(kp + ks*16);
        acc = __builtin_amdgcn_mfma_f32_32x32x16_bf16(a, bb, acc, 0,0,0);
    }
    float* op = part + ((size_t)chunk*16 + bh)*1024;
    const int col = l & 31;
#pragma unroll
    for (int r=0;r<16;r++){
        int row = (r&3) + 8*(r>>2) + 4*(l>>5);
        op[row*32 + col] = acc[r];
    }
}

// ============ softmax (fused chunk-reduce; norms + temp folded) ============
__global__ __launch_bounds__(576) void softmax_kernel(
    const float* __restrict__ part, const float* __restrict__ invq,
    const float* __restrict__ invk, const float* __restrict__ temp,
    float* __restrict__ attn)
{
    __shared__ float l[576];
    const int bh=blockIdx.x, b=bh>>2, h=bh&3;
    const int tid=threadIdx.x;
    const int i=tid/24, j=tid-i*24;
    float s=0.f;
    for (int c=0;c<32;c++) s += part[((size_t)c*16 + bh)*1024 + i*32 + j];
    l[tid] = s * invq[b*96+h*24+i] * invk[b*96+h*24+j] * temp[h];
    __syncthreads();
    if(tid<24){
        float m=-1e30f;
#pragma unroll
        for(int jj=0;jj<24;jj++) m = fmaxf(m, l[tid*24+jj]);
        float e[24]; float sm=0.f;
#pragma unroll
        for(int jj=0;jj<24;jj++){ e[jj]=__expf(l[tid*24+jj]-m); sm+=e[jj]; }
        float isv = 1.f/sm;
#pragma unroll
        for(int jj=0;jj<24;jj++) attn[(size_t)bh*576 + tid*24 + jj] = e[jj]*isv;
    }
}

// ============ M_b = po_w @ blockdiag(attn_b), packed to B-frag bf16 ============
__global__ __launch_bounds__(256) void mkM_kernel(
    const float* __restrict__ attn, const float* __restrict__ po_w,
    ushortT* __restrict__ Mpk)
{
    const int b = blockIdx.x;
    for (int e = threadIdx.x; e < 9216; e += 256){
        int oc = e / 96, d = e - oc*96;
        int h = d / 24, dl = d - h*24;
        const float* aw = attn + ((size_t)(b*4+h))*576 + dl;
        const float* pw = po_w + (size_t)oc*96 + h*24;
        float s = 0.f;
#pragma unroll
        for (int c=0;c<24;c++) s += pw[c]*aw[c*24];
        int ch = d>>5, kg = (d>>3)&3, j = d&7;
        Mpk[(size_t)b*9216 + ((size_t)(ch*4+kg)*96 + oc)*8 + j] = f2b(s);
    }
}

extern "C" void kernel_launch(void* const* d_in, const int* in_sizes, int n_in,
                              void* d_out, int out_size, void* d_ws, size_t ws_size,
                              hipStream_t stream)
{
    const float* x     = (const float*)d_in[0];
    const float* Lc_w1 = (const float*)d_in[1];
    const float* Lc_b1 = (const float*)d_in[2];
    const float* Lc_w2 = (const float*)d_in[3];
    const float* Lc_b2 = (const float*)d_in[4];
    const float* Rc_w1 = (const float*)d_in[5];
    const float* Rc_b1 = (const float*)d_in[6];
    const float* Rc_w2 = (const float*)d_in[7];
    const float* Rc_b2 = (const float*)d_in[8];
    const float* Lr_w  = (const float*)d_in[9];
    const float* Lr_b  = (const float*)d_in[10];
    const float* Rr_w  = (const float*)d_in[11];
    const float* Rr_b  = (const float*)d_in[12];
    const float* n1_w  = (const float*)d_in[13];
    const float* n1_b  = (const float*)d_in[14];
    const float* nL_w  = (const float*)d_in[15];
    const float* nL_b  = (const float*)d_in[16];
    const float* n2_w  = (const float*)d_in[17];
    const float* n2_b  = (const float*)d_in[18];
    const float* temp  = (const float*)d_in[19];
    const float* q_w   = (const float*)d_in[20];
    const float* qd_w  = (const float*)d_in[21];
    const float* kv_w  = (const float*)d_in[22];
    const float* kvd_w = (const float*)d_in[23];
    const float* po_w  = (const float*)d_in[24];
    const float* pi_w  = (const float*)d_in[25];
    const float* fdw_w = (const float*)d_in[26];
    const float* fpo_w = (const float*)d_in[27];

    char* base = (char*)d_ws;
    ushortT* xh   = (ushortT*)(base + 0);
    ushortT* f0h  = (ushortT*)(base + 0);
    ushortT* Lh   = (ushortT*)(base + 33554432);
    ushortT* kv0h = (ushortT*)(base + 33554432);
    ushortT* f1h  = (ushortT*)(base + 33554432);
    ushortT* Rh   = (ushortT*)(base + 67108864);
    ushortT* vh   = (ushortT*)(base + 67108864);
    ushortT* x2nh = (ushortT*)(base + 67108864);
    ushortT* illh = (ushortT*)(base + 79691776);
    ushortT* xnh  = (ushortT*)(base + 92274688);
    ushortT* q0h  = (ushortT*)(base + 104857600);
    ushortT* qb   = (ushortT*)(base + 117440512);
    float*   x1   = (float*)(base + 117440512);
    ushortT* kb   = (ushortT*)(base + 142606336);
    ushortT* Bb   = (ushortT*)(base + 155189248);
    char* smb = base + 167772160;
    ushortT* wpkL = (ushortT*)smb;   smb += 165888;
    ushortT* wpkR = (ushortT*)smb;   smb += 165888;
    ushortT* wpkQ = (ushortT*)smb;   smb += 165888;
    ushortT* wpkF = (ushortT*)smb;   smb += 1327104;
    ushortT* wq0  = (ushortT*)smb;   smb += 18432;
    ushortT* wkv  = (ushortT*)smb;   smb += 36864;
    ushortT* wpi  = (ushortT*)smb;   smb += 49152;
    ushortT* wfpo = (ushortT*)smb;   smb += 49152;
    ushortT* Mpk  = (ushortT*)smb;   smb += 73728;
    float* invqk  = (float*)smb;     smb += 3072;
    float* part   = (float*)smb;     smb += 2097152;
    float* attn   = (float*)smb;     smb += 36864;

    float* out_x = (float*)d_out;
    float* out_L = out_x + (size_t)4*96*HWsz;
    float* out_R = out_L + (size_t)4*HWsz;

    dim3 blk(256);

    // ---- packing + input convert (+ fused n1 LN) ----
    hipLaunchKernelGGL(pack_all_kernel, dim3(3864), blk, 0, stream,
        Lc_w1, Rc_w1, qd_w, fdw_w, q_w, kv_w, pi_w, fpo_w,
        wpkL, wpkR, wpkQ, wpkF, wq0, wkv, wpi, wfpo);
    hipLaunchKernelGGL(tonhwc_ln_kernel, dim3(64,4), blk, 0, stream, x, n1_w, n1_b, xh, xnh);

    // ---- Retinex heads (Lc+Rc, v4 single-tile, 3 blocks/CU) ----
    hipLaunchKernelGGL((conv3x3_v4<3,3,1,1,1>), dim3(64,4,4), blk, 0, stream,
        xh, wpkL, wpkR, Lc_b1, Rc_b1, Lh, Rh, 96, 96);
    hipLaunchKernelGGL((head1x1_kernel<1>), dim3(64,4), blk, 0, stream, Lh, Lc_w2, Lc_b2, out_L);
    hipLaunchKernelGGL((head1x1_kernel<3>), dim3(64,4), blk, 0, stream, Rh, Rc_w2, Rc_b2, out_R);
    hipLaunchKernelGGL(lrein_ln_kernel, dim3(64,4), blk, 0, stream, out_L, Lr_w, Lr_b, nL_w, nL_b, illh);
    hipLaunchKernelGGL(conv3x3_rr_kernel, dim3(64,12,4), blk, 0, stream, out_R, Rr_w, Rr_b, Bb);

    // ---- q path ----
    hipLaunchKernelGGL((gemm1x1_mfma<6,3,0,1,0>), dim3(64,1,4), blk, 0, stream,
        illh, wq0, 0, nullptr, nullptr, (void*)q0h, 96, 96);
    hipLaunchKernelGGL((conv3x3_v4<3,3,0,0,2>), dim3(64,2,4), blk, 0, stream,
        q0h, wpkQ, wpkQ, nullptr, nullptr, qb, qb, 96, 0);
    // ---- kv path ----
    hipLaunchKernelGGL((gemm1x1_v2<3,3>), dim3(256,1,4), blk, 0, stream,
        xnh, wkv, kv0h, 192, 192);
    hipLaunchKernelGGL(dw_nhwc_kernel, dim3(64,24,4), blk, 0, stream, kv0h, kvd_w, kb, vh);

    // ---- attention ----
    hipLaunchKernelGGL(rownorm_bf16_kernel, dim3(768), blk, 0, stream, qb, kb, invqk);
    hipLaunchKernelGGL(qk_mfma_kernel, dim3(8,16), blk, 0, stream, qb, kb, part);
    hipLaunchKernelGGL(softmax_kernel, dim3(16), dim3(576), 0, stream, part, invqk, invqk+384, temp, attn);
    hipLaunchKernelGGL(mkM_kernel, dim3(4), blk, 0, stream, attn, po_w, Mpk);
    // fused pv+po + LN(n2): x1 = x + M@v ; x2nh = LN(x1)
    hipLaunchKernelGGL(pvpo_ln_kernel, dim3(64,1,4), blk, 0, stream,
        vh, Mpk, x, n2_w, n2_b, x1, x2nh);

    // ---- FFN ----
    hipLaunchKernelGGL((gemm1x1_v2<4,3>), dim3(256,1,4), blk, 0, stream,
        x2nh, wpi, f0h, 255, 256);
    hipLaunchKernelGGL((conv3x3_v4<3,8,1,0,1>), dim3(64,6,4), blk, 0, stream,
        f0h, wpkF, wpkF, nullptr, nullptr, f1h, f1h, 255, 256);
    hipLaunchKernelGGL((gemm1x1_mfma<6,8,2,0,0>), dim3(64,1,4), blk, 0, stream,
        f1h, wfpo, 0, x1, Bb, (void*)out_x, 96, 0);
}